// Round 10
// baseline (96.896 us; speedup 1.0000x reference)
//
#include <hip/hip_runtime.h>

#define NFRAME 2
#define NATOMS 4096
#define NNEI 138
#define SEL0 46
#define N1 24
#define N2 48
#define N3 96

// ---- workspace layout (BYTE offsets) ----
#define WS_W2F 0        // [2 seg][3 nt][64 lane][16B] bf16 W2 B-frags = 6144 B
#define WS_W3F 8192     // [2 seg][6 nt][2 ks][64 lane][16B] bf16 W3 B-frags = 24576 B
#define WS_SF  32768    // [3 ntl][2 ks][64 lane][16B] identity-48 B-frags = 6144 B
#define WS_SF2 38912    // [3 ntl][64 lane][16B] concat-24 B-frags = 3072 B

// ---- LDS layout (BYTE offsets) ----
// Half-size GF: [3 ntl][5 ks][64 lane][16B] = 15360 B, reused by both stage-D halves.
// GF aliases X2 (0..14976) + head of H1 — both dead after barrier 3.
#define GFB 0
#define GFS 5120        // per-ntl stride
#define X2B 0           // 144 rows x 104 B bf16 x2 = 14976
#define X2S 104
#define H1B 14976       // 144 rows x 56 B bf16 h1 + 8 B phantom = 8072 -> ends 23048
#define H1S 56
#define DFB 23056       // d in A-frag layout, compact cl<4: [5 ks][16 slot][16B] = 1280 B -> 24336
#define GRBB 0          // gr 4x96 f32 = 1536 B, aliases GF after all gr reads
#define SMEM_BYTES 24576 // -> 6 blocks/CU (147456 <= 163840)

using short8 = __attribute__((ext_vector_type(8))) short;
using f32x4  = __attribute__((ext_vector_type(4))) float;

__device__ __forceinline__ float fexp2(float x) {
#if __has_builtin(__builtin_amdgcn_exp2f)
    return __builtin_amdgcn_exp2f(x);
#else
    return exp2f(x);
#endif
}
__device__ __forceinline__ float frcp(float x) {
#if __has_builtin(__builtin_amdgcn_rcpf)
    return __builtin_amdgcn_rcpf(x);
#else
    return 1.0f / x;
#endif
}
// tanh(x) = 1 - 2/(exp(2x)+1); saturates for |x| large
__device__ __forceinline__ float fast_tanh(float x) {
    float e = fexp2(x * 2.8853900817779268f);
    return 1.0f - 2.0f * frcp(e + 1.0f);
}
// RNE f32 -> bf16 bits (prep kernel)
__device__ __forceinline__ unsigned int f2bf(float f) {
    unsigned int u = __float_as_uint(f);
    return (u + 0x7fffu + ((u >> 16) & 1u)) >> 16;
}
// hot path: 1-instr packed convert, lo = bf16(a), hi = bf16(b)
__device__ __forceinline__ unsigned int cvt_pk_bf16(float a, float b) {
    unsigned int r;
    asm("v_cvt_pk_bf16_f32 %0, %1, %2" : "=v"(r) : "v"(a), "v"(b));
    return r;
}

// ---- pre-kernel: pack W2/W3/S/S2 into bf16 fragment-major B-operand layouts ----
__global__ void prep_kernel(const float* __restrict__ W2,
                            const float* __restrict__ W3,
                            unsigned char* __restrict__ ws)
{
    const int c = blockIdx.x * 256 + threadIdx.x;   // 16B-chunk id
    const int lane = c & 63;
    const int cl = lane & 15, grp = lane >> 4;
    unsigned short v[8];
    if (c < 384) {                                  // W2 frags
        const int fi = c >> 6;                      // 0..5
        const int seg = fi / 3, nt = fi % 3;
        const int col = nt * 16 + cl;
        #pragma unroll
        for (int j = 0; j < 8; ++j) {
            const int k = grp * 8 + j;
            const float fv = (k < N1) ? W2[(seg * N1 + k) * N2 + col] : 0.0f;
            v[j] = (unsigned short)f2bf(fv);
        }
    } else if (c >= 512 && c < 2048) {              // W3 frags
        const int cc = c - 512;
        const int fi = cc >> 6;                     // 0..23
        const int seg = fi / 12, r = fi % 12, nt = r >> 1, ks = r & 1;
        const int col = nt * 16 + cl;
        #pragma unroll
        for (int j = 0; j < 8; ++j) {
            const int k = ks * 32 + grp * 8 + j;
            const float fv = (k < N2) ? W3[(seg * N2 + k) * N3 + col] : 0.0f;
            v[j] = (unsigned short)f2bf(fv);
        }
    } else if (c >= 2048 && c < 2432) {             // S: identity-48 (x2 skip)
        const int cc = c - 2048;
        const int fi = cc >> 6;                     // 0..5
        const int ntl = fi >> 1, ks = fi & 1;
        const int col = ntl * 16 + cl;
        #pragma unroll
        for (int j = 0; j < 8; ++j) {
            const int k = ks * 32 + grp * 8 + j;
            v[j] = (k == col) ? (unsigned short)0x3F80 : (unsigned short)0;
        }
    } else if (c >= 2432 && c < 2624) {             // S2: concat-24 (h1 skip)
        const int cc = c - 2432;
        const int ntl = cc >> 6;                    // 0..2
        const int col = ntl * 16 + cl;
        const int cm = (col < 24) ? col : (col - 24);
        #pragma unroll
        for (int j = 0; j < 8; ++j) {
            const int k = grp * 8 + j;
            v[j] = (k == cm) ? (unsigned short)0x3F80 : (unsigned short)0;
        }
    } else {
        return;
    }
    uint4 q;
    q.x = (unsigned)v[0] | ((unsigned)v[1] << 16);
    q.y = (unsigned)v[2] | ((unsigned)v[3] << 16);
    q.z = (unsigned)v[4] | ((unsigned)v[5] << 16);
    q.w = (unsigned)v[6] | ((unsigned)v[7] << 16);
    int off;
    if (c < 384)       off = WS_W2F + c * 16;
    else if (c < 2048) off = WS_W3F + (c - 512) * 16;
    else if (c < 2432) off = WS_SF  + (c - 2048) * 16;
    else               off = WS_SF2 + (c - 2432) * 16;
    *reinterpret_cast<uint4*>(ws + off) = q;
}

__global__ __launch_bounds__(192) __attribute__((amdgpu_waves_per_eu(4)))
void descrpt_sea_kernel(
    const float* __restrict__ coord,
    const float* __restrict__ davg,
    const float* __restrict__ dstd,
    const float* __restrict__ W1, const float* __restrict__ b1,
    const float* __restrict__ W2, const float* __restrict__ b2,
    const float* __restrict__ W3, const float* __restrict__ b3,
    const int* __restrict__ atype, const int* __restrict__ nlist,
    const unsigned char* __restrict__ ws,
    float* __restrict__ out)
{
    __shared__ float smemf[SMEM_BYTES / 4];
    unsigned char* smemb = reinterpret_cast<unsigned char*>(smemf);

    const int bid  = blockIdx.x;          // f*NATOMS + n
    const int f    = bid >> 12;
    const int tid  = threadIdx.x;
    const int wid  = tid >> 6;
    const int lane = tid & 63;
    const int cl   = lane & 15;
    const int grp  = lane >> 4;

    // lane -> neighbor; padded rows: seg0 -> 0..45 (pad 46,47), seg1 -> 48..139 (pad 140..143)
    int i;
    bool active;
    if (wid == 0)      { i = lane;             active = (lane < SEL0); }
    else if (wid == 1) { i = SEL0 + lane;      active = true; }
    else               { i = SEL0 + 64 + lane; active = (i < NNEI); }
    const int tseg = __builtin_amdgcn_readfirstlane((wid == 0) ? 0 : 1);
    const int prow = (i < SEL0) ? i : (i + 2);

    const float* b2p = b2 + tseg * N2;
    const float* b3p = b3 + tseg * N3;
    float b2v[3], b3v[6];
    #pragma unroll
    for (int nt = 0; nt < 3; ++nt) b2v[nt] = b2p[nt * 16 + cl];
    #pragma unroll
    for (int nt = 0; nt < 6; ++nt) b3v[nt] = b3p[nt * 16 + cl];

    const float cx = coord[bid * 3 + 0];
    const float cy = coord[bid * 3 + 1];
    const float cz = coord[bid * 3 + 2];
    const int at = atype[bid];

    const float* W1p = W1 + tseg * N1;
    const float* b1p = b1 + tseg * N1;

    // ---- zero fills (all disjoint from producer writes; no barrier needed) ----
    // DF slots with no producer: rows {46,47} u {140..159}, 4 a-slots each
    if (tid < 88) {
        const int t = tid >> 2;                          // 0..21
        const int row = (t < 2) ? (46 + t) : (138 + t);  // 46,47,140..159
        const int a = tid & 3;
        const int byte = DFB + ((row >> 5) << 8) + ((((row >> 3) & 3) * 4 + a) << 4)
                       + ((row & 7) << 1);
        *reinterpret_cast<unsigned short*>(smemb + byte) = 0;
    }
    // h1 row tails (8B at +48) for all 144 rows
    if (tid < 144)
        *reinterpret_cast<uint2*>(smemb + H1B + tid * H1S + 48) = (uint2){0u, 0u};
    // phantom 8 B after row 143 (row 143 grp3 overrun)
    if (tid < 2)
        *reinterpret_cast<unsigned int*>(smemb + H1B + 144 * H1S + tid * 4) = 0u;
    // pad-atom h1 rows {46,47,140..143} fully zero (56 B = 14 words each)
    if (tid < 84) {
        const int ri = tid / 14;
        const int row = (ri < 2) ? (46 + ri) : (138 + ri);
        *reinterpret_cast<unsigned int*>(smemb + H1B + row * H1S + (tid % 14) * 4) = 0u;
    }

    // ---- phase 1: environment matrix d (-> DF A-frag slots, bf16) + stage B (h1) ----
    if (active) {
        const int nl = nlist[bid * NNEI + i];
        const float* nc = coord + ((size_t)f * NATOMS + (size_t)nl) * 3;
        float dx = nc[0] - cx, dy = nc[1] - cy, dz = nc[2] - cz;
        float rsq = dx * dx + dy * dy + dz * dz;
        float r = sqrtf(fmaxf(rsq, 1e-12f));
        float uu = (r - 0.5f) * (1.0f / 5.5f);
        float vv = uu * uu * uu * (uu * (-6.0f * uu + 15.0f) - 10.0f) + 1.0f;
        float sw = (r < 0.5f) ? 1.0f : ((r < 6.0f) ? vv : 0.0f);
        float rinv = frcp(r);
        float s = sw * rinv;
        float sor = s * rinv;
        const float* avg  = davg + ((size_t)at * NNEI + i) * 4;
        const float* stdp = dstd + ((size_t)at * NNEI + i) * 4;
        const float d0 = (s        - avg[0]) * frcp(stdp[0]);
        const float d1 = (sor * dx - avg[1]) * frcp(stdp[1]);
        const float d2 = (sor * dy - avg[2]) * frcp(stdp[2]);
        const float d3 = (sor * dz - avg[3]) * frcp(stdp[3]);

        // d -> DF A-frag slots: A[a][k=prow] = d[prow][a] (bf16)
        const unsigned int u01 = cvt_pk_bf16(d0, d1);
        const unsigned int u23 = cvt_pk_bf16(d2, d3);
        const int dbase = DFB + ((prow >> 5) << 8) + ((((prow >> 3) & 3) * 4) << 4)
                        + ((prow & 7) << 1);
        *reinterpret_cast<unsigned short*>(smemb + dbase +  0) = (unsigned short)u01;
        *reinterpret_cast<unsigned short*>(smemb + dbase + 16) = (unsigned short)(u01 >> 16);
        *reinterpret_cast<unsigned short*>(smemb + dbase + 32) = (unsigned short)u23;
        *reinterpret_cast<unsigned short*>(smemb + dbase + 48) = (unsigned short)(u23 >> 16);

        // stage B: h1 = tanh(x*W1 + b1) -> bf16 LDS row
        const float x = d0;
        #pragma unroll
        for (int c = 0; c < 3; ++c) {
            unsigned int u[4];
            #pragma unroll
            for (int p = 0; p < 4; ++p) {
                const float h0 = fast_tanh(fmaf(x, W1p[c * 8 + p * 2 + 0], b1p[c * 8 + p * 2 + 0]));
                const float h2 = fast_tanh(fmaf(x, W1p[c * 8 + p * 2 + 1], b1p[c * 8 + p * 2 + 1]));
                u[p] = cvt_pk_bf16(h0, h2);
            }
            uint4 w; w.x = u[0]; w.y = u[1]; w.z = u[2]; w.w = u[3];
            *reinterpret_cast<uint4*>(smemb + H1B + prow * H1S + c * 16) = w;
        }
    }

    __syncthreads();   // barrier 1: h1, DF ready

    // ---- stage C: X2 = (H1 @ S2) + tanh(H1 @ W2 + b2) via MFMA ----
    short8 aC[3];
    #pragma unroll
    for (int mt = 0; mt < 3; ++mt) {
        const int row = (wid * 3 + mt) * 16 + cl;
        // grp3 reads k=24..31 -> zeroed pad + next row head; W2/S2 frags zero for k>=24
        aC[mt] = *reinterpret_cast<const short8*>(smemb + H1B + row * H1S + grp * 16);
    }
    #pragma unroll
    for (int nt = 0; nt < 3; ++nt) {
        const short8 wf = *reinterpret_cast<const short8*>(ws + WS_W2F + (tseg * 3 + nt) * 1024 + lane * 16);
        const short8 s2 = *reinterpret_cast<const short8*>(ws + WS_SF2 + nt * 1024 + lane * 16);
        f32x4 acc[3], ask[3];
        #pragma unroll
        for (int mt = 0; mt < 3; ++mt) {
            f32x4 c0; c0[0] = b2v[nt]; c0[1] = b2v[nt]; c0[2] = b2v[nt]; c0[3] = b2v[nt];
            acc[mt] = __builtin_amdgcn_mfma_f32_16x16x32_bf16(aC[mt], wf, c0, 0, 0, 0);
            ask[mt] = __builtin_amdgcn_mfma_f32_16x16x32_bf16(aC[mt], s2,
                         (f32x4){0.f, 0.f, 0.f, 0.f}, 0, 0, 0);
        }
        #pragma unroll
        for (int mt = 0; mt < 3; ++mt) {
            #pragma unroll
            for (int q = 0; q < 4; ++q) {
                const int r = (wid * 3 + mt) * 16 + grp * 4 + q;
                const float x2v = ask[mt][q] + fast_tanh(acc[mt][q]);
                *reinterpret_cast<unsigned short*>(smemb + X2B + r * X2S + 2 * (nt * 16 + cl)) =
                    (unsigned short)cvt_pk_bf16(x2v, x2v);
            }
        }
    }

    __syncthreads();   // barrier 2: X2 complete, H1 dead

    // ---- load A-frags (x2) for stage D ----
    const short8 zero8 = (short8){0,0,0,0,0,0,0,0};
    short8 a0[3], a1[3];
    #pragma unroll
    for (int mt = 0; mt < 3; ++mt) {
        const int row = (wid * 3 + mt) * 16 + cl;
        a0[mt] = *reinterpret_cast<const short8*>(smemb + X2B + row * X2S + grp * 16);
        short8 t = *reinterpret_cast<const short8*>(smemb + X2B + row * X2S + 64 + (grp & 1) * 16);
        a1[mt] = (grp < 2) ? t : zero8;   // zero k=48..63
    }

    __syncthreads();   // barrier 3: A-frags loaded -> X2 dead, GF region writable

    // GF tail zero: ks=4 lanes 32..63 (k=144..159) of all 3 local slots — stays
    // zero through both halves (epilogues only touch real-row slots)
    if (tid < 96) {
        const int ntl = tid >> 5, slot = tid & 31;
        uint4 z; z.x = 0u; z.y = 0u; z.z = 0u; z.w = 0u;
        *reinterpret_cast<uint4*>(smemb + GFB + ntl * GFS + 4096 + (32 + slot) * 16) = z;
    }

    // d A-frags (DF stable since barrier 1; reused by both gr halves)
    short8 af[5];
    #pragma unroll
    for (int ks = 0; ks < 5; ++ks) {
        short8 v = zero8;
        if (cl < 4)
            v = *reinterpret_cast<const short8*>(smemb + DFB + (ks << 8) + ((grp * 4 + cl) << 4));
        af[ks] = v;
    }

    // ---- stage D + gr in two halves over a single half-size GF buffer ----
    const unsigned char* w3p = ws + WS_W3F + tseg * 12288 + lane * 16;
    f32x4 racc[2];
    #pragma unroll
    for (int h = 0; h < 2; ++h) {
        if (h == 1) __syncthreads();   // gr half-0 reads done -> GF overwrite safe
        #pragma unroll
        for (int ntl = 0; ntl < 3; ++ntl) {
            const int ntg = h * 3 + ntl;
            // askip = X2 @ I48 slice (skip connection)
            f32x4 askip[3];
            {
                const short8 sf0 = *reinterpret_cast<const short8*>(ws + WS_SF + (ntl * 2 + 0) * 1024 + lane * 16);
                const short8 sf1 = *reinterpret_cast<const short8*>(ws + WS_SF + (ntl * 2 + 1) * 1024 + lane * 16);
                #pragma unroll
                for (int mt = 0; mt < 3; ++mt) {
                    f32x4 t = __builtin_amdgcn_mfma_f32_16x16x32_bf16(a0[mt], sf0,
                                 (f32x4){0.f, 0.f, 0.f, 0.f}, 0, 0, 0);
                    askip[mt] = __builtin_amdgcn_mfma_f32_16x16x32_bf16(a1[mt], sf1, t, 0, 0, 0);
                }
            }
            const short8 bk0 = *reinterpret_cast<const short8*>(w3p + ntg * 2048);
            const short8 bk1 = *reinterpret_cast<const short8*>(w3p + ntg * 2048 + 1024);
            const float b = b3v[ntg];
            f32x4 acc[3];
            #pragma unroll
            for (int mt = 0; mt < 3; ++mt) {
                f32x4 c0; c0[0] = b; c0[1] = b; c0[2] = b; c0[3] = b;
                c0 = __builtin_amdgcn_mfma_f32_16x16x32_bf16(a0[mt], bk0, c0, 0, 0, 0);
                acc[mt] = __builtin_amdgcn_mfma_f32_16x16x32_bf16(a1[mt], bk1, c0, 0, 0, 0);
            }
            // epilogue: G = askip + tanh(acc) -> bf16 -> GF B-frag slots (uint2 each)
            #pragma unroll
            for (int mt = 0; mt < 3; ++mt) {
                const int row0 = (wid * 3 + mt) * 16 + grp * 4;
                const int ks = row0 >> 5;
                const int gp = (row0 >> 3) & 3;
                const float g0 = askip[mt][0] + fast_tanh(acc[mt][0]);
                const float g1 = askip[mt][1] + fast_tanh(acc[mt][1]);
                const float g2 = askip[mt][2] + fast_tanh(acc[mt][2]);
                const float g3 = askip[mt][3] + fast_tanh(acc[mt][3]);
                uint2 w;
                w.x = cvt_pk_bf16(g0, g1);
                w.y = cvt_pk_bf16(g2, g3);
                *reinterpret_cast<uint2*>(smemb + GFB + ntl * GFS + ks * 1024
                                          + ((gp * 16 + cl) << 4) + ((grp & 1) << 3)) = w;
            }
        }
        __syncthreads();   // GF half ready
        // gr = d^T G for this half: wave wid owns local slot wid (ntg = h*3+wid)
        f32x4 r = (f32x4){0.f, 0.f, 0.f, 0.f};
        #pragma unroll
        for (int ks = 0; ks < 5; ++ks) {
            const short8 bg = *reinterpret_cast<const short8*>(
                smemb + GFB + wid * GFS + ks * 1024 + lane * 16);
            r = __builtin_amdgcn_mfma_f32_16x16x32_bf16(af[ks], bg, r, 0, 0, 0);
        }
        racc[h] = r;
    }

    __syncthreads();   // all GF reads done -> GRBB alias safe

    if (grp == 0) {
        const float inv = 1.0f / (float)NNEI;
        #pragma unroll
        for (int h = 0; h < 2; ++h) {
            const int ntg = h * 3 + wid;
            #pragma unroll
            for (int q = 0; q < 4; ++q)
                *reinterpret_cast<float*>(smemb + GRBB + (q * 96 + ntg * 16 + cl) * 4) =
                    racc[h][q] * inv;
        }
    }

    __syncthreads();   // gr ready

    // ---- phase 3: D[m][k] = sum_a gr[a][m]*gr[a][k], k<8 ----
    {
        const float* gr = reinterpret_cast<const float*>(smemb + GRBB);
        const size_t base = (size_t)bid * 768;
        #pragma unroll
        for (int rep = 0; rep < 4; ++rep) {
            const int o  = tid + rep * 192;
            const int mm = o >> 3;
            const int kk = o & 7;
            float a0v = 0.f;
            #pragma unroll
            for (int a = 0; a < 4; ++a)
                a0v = fmaf(gr[a * 96 + mm], gr[a * 96 + kk], a0v);
            out[base + o] = a0v;
        }
    }
}

extern "C" void kernel_launch(void* const* d_in, const int* in_sizes, int n_in,
                              void* d_out, int out_size, void* d_ws, size_t ws_size,
                              hipStream_t stream) {
    const float* coord = (const float*)d_in[0];
    const float* davg  = (const float*)d_in[1];
    const float* dstd  = (const float*)d_in[2];
    const float* W1    = (const float*)d_in[3];
    const float* b1    = (const float*)d_in[4];
    const float* W2    = (const float*)d_in[5];
    const float* b2    = (const float*)d_in[6];
    const float* W3    = (const float*)d_in[7];
    const float* b3    = (const float*)d_in[8];
    const int*   atype = (const int*)d_in[9];
    const int*   nlist = (const int*)d_in[10];
    float* out = (float*)d_out;
    unsigned char* ws = (unsigned char*)d_ws;

    prep_kernel<<<dim3(11), dim3(256), 0, stream>>>(W2, W3, ws);
    descrpt_sea_kernel<<<dim3(NFRAME * NATOMS), dim3(192), 0, stream>>>(
        coord, davg, dstd, W1, b1, W2, b2, W3, b3, atype, nlist, ws, out);
}